// Round 1
// baseline (1113.845 us; speedup 1.0000x reference)
//
#include <hip/hip_runtime.h>
#include <stdint.h>

#define BB_ 64
#define TT_ 4096
#define CC_ 192
#define TILE_ 64
#define HALO_ 13
#define TW_ 90
#define HS_ 92      // h row stride (floats)
#define YCS_ 104    // yc row stride (bf16)
#define YTS_ 200    // y_t row stride (bf16)

typedef float f32x4 __attribute__((ext_vector_type(4)));
typedef short s16x4 __attribute__((ext_vector_type(4)));
typedef short s16x8 __attribute__((ext_vector_type(8)));

__device__ __forceinline__ float bf2f(short s){
  uint32_t u = ((uint32_t)(uint16_t)s) << 16;
  float f; __builtin_memcpy(&f, &u, 4); return f;
}
__device__ __forceinline__ short f2bf(float f){
  uint32_t u; __builtin_memcpy(&u, &f, 4);
  u += 0x7FFFu + ((u >> 16) & 1u);   // RNE
  return (short)(u >> 16);
}
__device__ __forceinline__ float gelu_f(float x){
  return 0.5f * x * (1.0f + erff(x * 0.70710678118654752f));
}

// ---- depthwise conv (dilation D, kernel 3) : h[c][t]*mask -> yc[c][t] (bf16)
template<int D>
__device__ __forceinline__ void dw_pass(const float* __restrict__ H, short* __restrict__ YC,
    const float* __restrict__ MB, const float* __restrict__ sw, const float* __restrict__ sb, int tid){
  constexpr int WB = (D==9) ? 12 : 4;     // window back-offset (4-aligned)
  constexpr int NW = (D==9) ? 9 : 4;      // # float4 window loads
  for (int g = tid; g < CC_*12; g += 512){
    int c = g % CC_, jg = g / CC_;
    int j0 = jg*8;
    float w0 = sw[c*3+0], w1 = sw[c*3+1], w2 = sw[c*3+2], bb = sb[c];
    float pm[NW*4];
    const float* hrow = H + c*HS_ + j0 - WB;
    const float* mrow = MB + 16 + j0 - WB;
    #pragma unroll
    for (int q2 = 0; q2 < NW; ++q2){
      f32x4 hv = *(const f32x4*)(hrow + q2*4);
      f32x4 mv = *(const f32x4*)(mrow + q2*4);
      pm[q2*4+0] = hv[0]*mv[0]; pm[q2*4+1] = hv[1]*mv[1];
      pm[q2*4+2] = hv[2]*mv[2]; pm[q2*4+3] = hv[3]*mv[3];
    }
    s16x8 o;
    #pragma unroll
    for (int j = 0; j < 8; ++j){
      float v = bb + w0*pm[WB+j-D] + w1*pm[WB+j] + w2*pm[WB+j+D];
      o[j] = f2bf(v);
    }
    *(s16x8*)(YC + c*YCS_ + j0) = o;
  }
}

// ---- channel-LN stats over c (192) for t in [0,96), partials then combine
__device__ __forceinline__ void ln_stats(const short* __restrict__ YC, float* __restrict__ PS, int tid){
  if (tid < 192){
    int t4 = tid % 24, cc = tid / 24;
    int ttv = t4*4;
    f32x4 s = {0.f,0.f,0.f,0.f}, q = {0.f,0.f,0.f,0.f};
    #pragma unroll 4
    for (int ci = 0; ci < 24; ++ci){
      int c = cc*24 + ci;
      s16x4 v = *(const s16x4*)(YC + c*YCS_ + ttv);
      #pragma unroll
      for (int e=0;e<4;e++){ float f = bf2f(v[e]); s[e] += f; q[e] += f*f; }
    }
    *(f32x4*)(PS + cc*96 + ttv) = s;
    *(f32x4*)(PS + 768 + cc*96 + ttv) = q;
  }
}
__device__ __forceinline__ void ln_combine(const float* __restrict__ PS, float* __restrict__ SM,
                                           float* __restrict__ SR, int tid){
  if (tid < 96){
    float s = 0.f, q = 0.f;
    #pragma unroll
    for (int cc=0; cc<8; ++cc){ s += PS[cc*96+tid]; q += PS[768+cc*96+tid]; }
    float mean = s*(1.0f/192.0f);
    float var = q*(1.0f/192.0f) - mean*mean;
    var = fmaxf(var, 0.0f);
    SM[tid] = mean;
    SR[tid] = rsqrtf(var + 1e-5f);
  }
}

__global__ __launch_bounds__(512, 2)
void convflow_main(
    const float* __restrict__ x, const float* __restrict__ xmask,
    const float* __restrict__ pre_w, const float* __restrict__ pre_b,
    const float* __restrict__ sep_w, const float* __restrict__ sep_b,
    const float* __restrict__ pw_b,
    const float* __restrict__ ln1_g, const float* __restrict__ ln1_b,
    const float* __restrict__ ln2_g, const float* __restrict__ ln2_b,
    const float* __restrict__ proj_b,
    const short* __restrict__ Wbf, const short* __restrict__ Pbf,
    float* __restrict__ out, float* __restrict__ part)
{
  __shared__ __align__(16) char smem_raw[150784];
  float* MB = (float*)(smem_raw + 0);        // [160]: mask, index j+16, zero outside [0,90)
  float* XB = (float*)(smem_raw + 640);      // [96]
  float* SM = (float*)(smem_raw + 1024);     // [96]
  float* SR = (float*)(smem_raw + 1408);     // [96]
  float* H  = (float*)(smem_raw + 1792);     // [192][92] fp32
  short* YC = (short*)(smem_raw + 72448);    // [192][104] bf16
  short* YT = (short*)(smem_raw + 112384);   // [96][200] bf16
  float* PS = (float*)(smem_raw + 112384);   // alias on YT: [2][8][96] partial sums
  float* HP = (float*)(smem_raw + 72448);    // alias on YC: [64][33] proj output

  const int tid = threadIdx.x;
  const int b = blockIdx.y, tile = blockIdx.x;
  const int t0 = tile*TILE_ - HALO_;

  // ---- setup mask + x0 window
  for (int idx = tid; idx < 160; idx += 512){
    int j = idx - 16; int t = t0 + j;
    float m = 0.f;
    if (j >= 0 && j < TW_ && t >= 0 && t < TT_) m = xmask[b*TT_ + t];
    MB[idx] = m;
  }
  for (int idx = tid; idx < 96; idx += 512){
    int t = t0 + idx; float v = 0.f;
    if (idx < TW_ && t >= 0 && t < TT_) v = x[(b*2)*TT_ + t];
    XB[idx] = v;
  }
  __syncthreads();
  // ---- h0 = pre_w * x0 + pre_b
  for (int g = tid; g < CC_*23; g += 512){
    int c = g / 23, jq = g - c*23;
    float w = pre_w[c], bb = pre_b[c];
    f32x4 xv = *(f32x4*)&XB[jq*4];
    f32x4 hv;
    #pragma unroll
    for (int e=0;e<4;e++) hv[e] = w*xv[e] + bb;
    *(f32x4*)&H[c*HS_ + jq*4] = hv;
  }
  __syncthreads();

  // ---- 3 WN layers
  #pragma unroll 1
  for (int li = 0; li < 3; ++li){
    const int jlo = (li==0) ? 1 : ((li==1) ? 4 : 13);
    const int jhi = (li==0) ? 89 : ((li==1) ? 86 : 77);
    const float* sw = sep_w + li*CC_*3;
    const float* sb = sep_b + li*CC_;

    if (li == 0)      dw_pass<1>(H, YC, MB, sw, sb, tid);
    else if (li == 1) dw_pass<3>(H, YC, MB, sw, sb, tid);
    else              dw_pass<9>(H, YC, MB, sw, sb, tid);
    __syncthreads();

    ln_stats(YC, PS, tid);  __syncthreads();
    ln_combine(PS, SM, SR, tid); __syncthreads();

    // ---- transpose + LN1 + gelu -> y_t[j][c] bf16 (zero outside valid rows)
    {
      const float* g1 = ln1_g + li*CC_;
      const float* b1 = ln1_b + li*CC_;
      for (int g = tid; g < 48*24; g += 512){
        int c4 = g % 48, t4 = g / 48;
        int c0 = c4*4, tt2 = t4*4;
        f32x4 g1v = *(const f32x4*)&g1[c0];
        f32x4 b1v = *(const f32x4*)&b1[c0];
        f32x4 mv = *(f32x4*)&SM[tt2], rv = *(f32x4*)&SR[tt2];
        float vals[4][4];
        #pragma unroll
        for (int rr=0; rr<4; rr++){
          s16x4 yv = *(s16x4*)&YC[(c0+rr)*YCS_ + tt2];
          #pragma unroll
          for (int e=0;e<4;e++)
            vals[rr][e] = (bf2f(yv[e]) - mv[e]) * rv[e] * g1v[rr] + b1v[rr];
        }
        #pragma unroll
        for (int e=0;e<4;e++){
          int t = tt2 + e;
          bool ok = (t >= jlo) && (t < jhi);
          s16x4 o;
          #pragma unroll
          for (int rr=0; rr<4; rr++)
            o[rr] = f2bf(ok ? gelu_f(vals[rr][e]) : 0.f);
          *(s16x4*)&YT[t*YTS_ + c0] = o;
        }
      }
    }
    __syncthreads();

    // ---- pointwise 192x192 GEMM via MFMA bf16: y2 = W*y + b -> yc[c2][j] bf16
    {
      int w = tid >> 6, lane = tid & 63, l16 = lane & 15, q = lane >> 4;
      int mq = w >> 1, nh = w & 1;
      f32x4 acc[3][3];
      #pragma unroll
      for (int r=0;r<3;r++)
        #pragma unroll
        for (int s=0;s<3;s++){ f32x4 z = {0.f,0.f,0.f,0.f}; acc[r][s] = z; }
      const short* Wl = Wbf + li*CC_*CC_;
      #pragma unroll
      for (int kk=0; kk<6; ++kk){
        s16x8 a[3], bv[3];
        #pragma unroll
        for (int r=0;r<3;r++)
          a[r] = *(const s16x8*)&Wl[((mq*3+r)*16 + l16)*CC_ + kk*32 + q*8];
        #pragma unroll
        for (int s=0;s<3;s++)
          bv[s] = *(const s16x8*)&YT[((nh*3+s)*16 + l16)*YTS_ + kk*32 + q*8];
        #pragma unroll
        for (int r=0;r<3;r++)
          #pragma unroll
          for (int s=0;s<3;s++)
            acc[r][s] = __builtin_amdgcn_mfma_f32_16x16x32_bf16(a[r], bv[s], acc[r][s], 0, 0, 0);
      }
      #pragma unroll
      for (int r=0;r<3;r++){
        #pragma unroll
        for (int e=0;e<4;e++){
          int m = (mq*3+r)*16 + q*4 + e;
          float bias = pw_b[li*CC_ + m];
          #pragma unroll
          for (int s=0;s<3;s++){
            int j = (nh*3+s)*16 + l16;
            YC[m*YCS_ + j] = f2bf(acc[r][s][e] + bias);
          }
        }
      }
    }
    __syncthreads();

    ln_stats(YC, PS, tid);  __syncthreads();
    ln_combine(PS, SM, SR, tid); __syncthreads();

    // ---- LN2 + gelu + residual into h (all j in [0,92); garbage cols provably unused)
    {
      const float* g2 = ln2_g + li*CC_;
      const float* b2 = ln2_b + li*CC_;
      for (int g = tid; g < CC_*23; g += 512){
        int c = g / 23, jq = g - c*23;
        int j0 = jq*4;
        float gc = g2[c], bc = b2[c];
        s16x4 yv = *(s16x4*)&YC[c*YCS_ + j0];
        f32x4 mv = *(f32x4*)&SM[j0], rv = *(f32x4*)&SR[j0];
        f32x4 hv = *(f32x4*)&H[c*HS_ + j0];
        #pragma unroll
        for (int e=0;e<4;e++){
          float v = (bf2f(yv[e]) - mv[e]) * rv[e] * gc + bc;
          hv[e] += gelu_f(v);
        }
        *(f32x4*)&H[c*HS_ + j0] = hv;
      }
    }
    __syncthreads();
  }

  // ---- proj input transpose: y_t[n][c] = bf16(h[c][13+n] * mask)
  for (int g = tid; g < 64*CC_; g += 512){
    int n = g & 63, c = g >> 6;
    float v = H[c*HS_ + HALO_ + n] * MB[16 + HALO_ + n];
    YT[n*YTS_ + c] = f2bf(v);
  }
  __syncthreads();
  // ---- proj GEMM (32x192 @ 192x64) via MFMA -> HP[n][m], bias + mask applied
  {
    int w = tid >> 6;
    if (w < 4){
      int lane = tid & 63, l16 = lane & 15, q = lane >> 4;
      int mt = w >> 1, ntp = w & 1;
      f32x4 pacc[2];
      { f32x4 z = {0.f,0.f,0.f,0.f}; pacc[0] = z; pacc[1] = z; }
      #pragma unroll
      for (int kk=0; kk<6; ++kk){
        s16x8 a = *(const s16x8*)&Pbf[(mt*16 + l16)*CC_ + kk*32 + q*8];
        #pragma unroll
        for (int s=0;s<2;s++){
          s16x8 bv = *(const s16x8*)&YT[((ntp*2+s)*16 + l16)*YTS_ + kk*32 + q*8];
          pacc[s] = __builtin_amdgcn_mfma_f32_16x16x32_bf16(a, bv, pacc[s], 0, 0, 0);
        }
      }
      #pragma unroll
      for (int s=0;s<2;s++)
        #pragma unroll
        for (int e=0;e<4;e++){
          int m = mt*16 + q*4 + e;
          if (m < 29){
            int n = (ntp*2+s)*16 + l16;
            HP[n*33 + m] = (pacc[s][e] + proj_b[m]) * MB[16 + HALO_ + n];
          }
        }
    }
  }
  __syncthreads();

  // ---- rational-quadratic spline, one thread per t
  if (tid < 64){
    const int n = tid;
    const int tg = tile*TILE_ + n;
    const float msk = MB[16 + HALO_ + n];
    const float* hp = &HP[n*33];
    const float inv_s = 0.07216878364870323f;  // 1/sqrt(192)
    float uw[10], uh[10], ud9[9];
    #pragma unroll
    for (int k=0;k<10;k++){ uw[k] = hp[k]*inv_s; uh[k] = hp[10+k]*inv_s; }
    #pragma unroll
    for (int k=0;k<9;k++) ud9[k] = hp[20+k];

    float cumw[11], cumh[11];
    {
      float mx = uw[0];
      #pragma unroll
      for (int k=1;k<10;k++) mx = fmaxf(mx, uw[k]);
      float ex[10]; float ss = 0.f;
      #pragma unroll
      for (int k=0;k<10;k++){ ex[k] = __expf(uw[k]-mx); ss += ex[k]; }
      float inv = 1.0f/ss;
      cumw[0] = -5.f; float cw = 0.f;
      #pragma unroll
      for (int k=0;k<10;k++){ float wk = 0.001f + 0.99f*(ex[k]*inv); cw += wk; cumw[k+1] = 10.f*cw - 5.f; }
      cumw[10] = 5.f;
    }
    {
      float mx = uh[0];
      #pragma unroll
      for (int k=1;k<10;k++) mx = fmaxf(mx, uh[k]);
      float ex[10]; float ss = 0.f;
      #pragma unroll
      for (int k=0;k<10;k++){ ex[k] = __expf(uh[k]-mx); ss += ex[k]; }
      float inv = 1.0f/ss;
      cumh[0] = -5.f; float ch = 0.f;
      #pragma unroll
      for (int k=0;k<10;k++){ float hk = 0.001f + 0.99f*(ex[k]*inv); ch += hk; cumh[k+1] = 10.f*ch - 5.f; }
      cumh[10] = 5.f;
    }
    float dv[11];
    dv[0] = 1.0f; dv[10] = 1.0f;   // MIN_DERIV + softplus(log(exp(1-MIN_DERIV)-1)) == 1.0
    #pragma unroll
    for (int k=0;k<9;k++){
      float u = ud9[k];
      float sp = (u > 15.f) ? u : log1pf(__expf(u));
      dv[k+1] = 0.001f + sp;
    }

    const float x1 = x[(b*2+1)*TT_ + tg];
    const float xin = fminf(fmaxf(x1, -5.f), 5.f);
    int cnt = 0;
    #pragma unroll
    for (int k=0;k<11;k++){
      float lk = cumw[k] + ((k==10) ? 1e-6f : 0.f);
      cnt += (xin >= lk) ? 1 : 0;
    }
    int bin = cnt - 1;
    bin = (bin < 0) ? 0 : ((bin > 9) ? 9 : bin);

    float icw=0.f, iw=1.f, ich=0.f, ih=1.f, dl=1.f, dr=1.f;
    #pragma unroll
    for (int k=0;k<10;k++){
      if (bin == k){
        icw = cumw[k]; iw = cumw[k+1]-cumw[k];
        ich = cumh[k]; ih = cumh[k+1]-cumh[k];
        dl = dv[k]; dr = dv[k+1];
      }
    }
    float delta = ih/iw;
    float th = (xin - icw)/iw;
    float t1m = th*(1.f-th);
    float num = ih*(delta*th*th + dl*t1m);
    float den = delta + (dl + dr - 2.f*delta)*t1m;
    float yv = ich + num/den;
    float omt = 1.f - th;
    float dnum = delta*delta*(dr*th*th + 2.f*delta*t1m + dl*omt*omt);
    float lad = logf(dnum) - 2.f*logf(den);
    bool inside = (x1 >= -5.f) && (x1 <= 5.f);
    float outv = inside ? yv : x1;
    float ladv = inside ? lad : 0.f;

    out[(b*2)*TT_ + tg]   = x[(b*2)*TT_ + tg] * msk;
    out[(b*2+1)*TT_ + tg] = outv * msk;

    float lsum = ladv * msk;
    #pragma unroll
    for (int off = 32; off > 0; off >>= 1) lsum += __shfl_xor(lsum, off);
    if (tid == 0) part[b*64 + tile] = lsum;
  }
}

// ---- pre-pass: convert pw_w / proj_w to bf16 in workspace
__global__ void convflow_pre(const float* __restrict__ pw_w, const float* __restrict__ proj_w,
                             short* __restrict__ Wbf, short* __restrict__ Pbf){
  int idx = blockIdx.x*256 + threadIdx.x;
  if (idx < 110592) Wbf[idx] = f2bf(pw_w[idx]);
  if (idx < 32*192){
    int m = idx / 192, k = idx - m*192;
    Pbf[idx] = (m < 29) ? f2bf(proj_w[m*192 + k]) : (short)0;
  }
}

// ---- logdet reduction: 64 tiles per batch
__global__ void convflow_logdet(const float* __restrict__ part, float* __restrict__ out){
  int bb = threadIdx.x;
  if (bb < 64){
    float s = 0.f;
    for (int k=0;k<64;k++) s += part[bb*64 + k];
    out[524288 + bb] = s;
  }
}

extern "C" void kernel_launch(void* const* d_in, const int* in_sizes, int n_in,
                              void* d_out, int out_size, void* d_ws, size_t ws_size,
                              hipStream_t stream) {
  const float* x      = (const float*)d_in[0];
  const float* xmask  = (const float*)d_in[1];
  const float* pre_w  = (const float*)d_in[2];
  const float* pre_b  = (const float*)d_in[3];
  const float* sep_w  = (const float*)d_in[4];
  const float* sep_b  = (const float*)d_in[5];
  const float* pw_w   = (const float*)d_in[6];
  const float* pw_b   = (const float*)d_in[7];
  const float* ln1_g  = (const float*)d_in[8];
  const float* ln1_b  = (const float*)d_in[9];
  const float* ln2_g  = (const float*)d_in[10];
  const float* ln2_b  = (const float*)d_in[11];
  const float* proj_w = (const float*)d_in[12];
  const float* proj_b = (const float*)d_in[13];

  short* Wbf = (short*)d_ws;                              // 3*192*192 bf16 = 221184 B
  short* Pbf = (short*)((char*)d_ws + 221184);            // 32*192 bf16 = 12288 B
  float* part = (float*)((char*)d_ws + 233472);           // 4096 floats
  float* out = (float*)d_out;

  convflow_pre<<<432, 256, 0, stream>>>(pw_w, proj_w, Wbf, Pbf);
  dim3 grid(64, 64);  // (tile, batch)
  convflow_main<<<grid, 512, 0, stream>>>(x, xmask, pre_w, pre_b, sep_w, sep_b, pw_b,
                                          ln1_g, ln1_b, ln2_g, ln2_b, proj_b,
                                          Wbf, Pbf, out, part);
  convflow_logdet<<<1, 64, 0, stream>>>(part, out);
}

// Round 2
// 709.359 us; speedup vs baseline: 1.5702x; 1.5702x over previous
//
#include <hip/hip_runtime.h>
#include <stdint.h>

#define BB_ 64
#define TT_ 4096
#define CC_ 192
#define TILE_ 64
#define HALO_ 13
#define TW_ 90
#define HS_ 92      // h row stride (floats)
#define YCS_ 104    // yc row stride (bf16)
#define YTS_ 200    // y_t row stride (bf16)
#define NT_ 1024

typedef float f32x4 __attribute__((ext_vector_type(4)));
typedef short s16x4 __attribute__((ext_vector_type(4)));
typedef short s16x8 __attribute__((ext_vector_type(8)));

__device__ __forceinline__ float bf2f(short s){
  uint32_t u = ((uint32_t)(uint16_t)s) << 16;
  float f; __builtin_memcpy(&f, &u, 4); return f;
}
__device__ __forceinline__ short f2bf(float f){
  uint32_t u; __builtin_memcpy(&u, &f, 4);
  u += 0x7FFFu + ((u >> 16) & 1u);   // RNE
  return (short)(u >> 16);
}
// tanh-form GELU: x*sigmoid(1.5957691*(x+0.044715*x^3)); |err| ~1e-3 << bf16 noise
__device__ __forceinline__ float gelu_f(float x){
  float t = x*x;
  float p = x*__builtin_fmaf(t, 0.0713548162f, 1.5957691216f);
  float e = __expf(-p);
  return x * __builtin_amdgcn_rcpf(1.0f + e);
}

// ---- depthwise conv (dilation D, kernel 3): H is PRE-MASKED -> yc[c][t] (bf16)
template<int D>
__device__ __forceinline__ void dw_pass(const float* __restrict__ H, short* __restrict__ YC,
    const float* __restrict__ sw, const float* __restrict__ sb, int tid){
  constexpr int WB = (D==9) ? 12 : 4;     // window back-offset (4-aligned)
  constexpr int NW = (D==9) ? 9 : 4;      // # float4 window loads
  for (int g = tid; g < CC_*12; g += NT_){
    int c = g % CC_, jg = g / CC_;
    int j0 = jg*8;
    float w0 = sw[c*3+0], w1 = sw[c*3+1], w2 = sw[c*3+2], bb = sb[c];
    float pm[NW*4];
    const float* hrow = H + c*HS_ + j0 - WB;
    #pragma unroll
    for (int q2 = 0; q2 < NW; ++q2){
      f32x4 hv = *(const f32x4*)(hrow + q2*4);
      pm[q2*4+0] = hv[0]; pm[q2*4+1] = hv[1];
      pm[q2*4+2] = hv[2]; pm[q2*4+3] = hv[3];
    }
    s16x8 o;
    #pragma unroll
    for (int j = 0; j < 8; ++j){
      float v = bb + w0*pm[WB+j-D] + w1*pm[WB+j] + w2*pm[WB+j+D];
      o[j] = f2bf(v);
    }
    *(s16x8*)(YC + c*YCS_ + j0) = o;
  }
}

// ---- channel-LN stats: 384 threads = 16 ch-groups x 24 t-quads, 12 ch each
__device__ __forceinline__ void ln_stats(const short* __restrict__ YC, float* __restrict__ PS, int tid){
  if (tid < 384){
    int t4 = tid % 24, cc = tid / 24;
    int ttv = t4*4;
    f32x4 s = {0.f,0.f,0.f,0.f}, q = {0.f,0.f,0.f,0.f};
    #pragma unroll 4
    for (int ci = 0; ci < 12; ++ci){
      int c = cc*12 + ci;
      s16x4 v = *(const s16x4*)(YC + c*YCS_ + ttv);
      #pragma unroll
      for (int e=0;e<4;e++){ float f = bf2f(v[e]); s[e] += f; q[e] += f*f; }
    }
    *(f32x4*)(PS + cc*96 + ttv) = s;
    *(f32x4*)(PS + 1536 + cc*96 + ttv) = q;
  }
}
__device__ __forceinline__ void ln_combine(const float* __restrict__ PS, float* __restrict__ SM,
                                           float* __restrict__ SR, int tid){
  if (tid < 96){
    float s = 0.f, q = 0.f;
    #pragma unroll
    for (int cc=0; cc<16; ++cc){ s += PS[cc*96+tid]; q += PS[1536+cc*96+tid]; }
    float mean = s*(1.0f/192.0f);
    float var = q*(1.0f/192.0f) - mean*mean;
    var = fmaxf(var, 0.0f);
    SM[tid] = mean;
    SR[tid] = rsqrtf(var + 1e-5f);
  }
}

__global__ __launch_bounds__(1024, 4)
void convflow_main(
    const float* __restrict__ x, const float* __restrict__ xmask,
    const float* __restrict__ pre_w, const float* __restrict__ pre_b,
    const float* __restrict__ sep_w, const float* __restrict__ sep_b,
    const float* __restrict__ pw_b,
    const float* __restrict__ ln1_g, const float* __restrict__ ln1_b,
    const float* __restrict__ ln2_g, const float* __restrict__ ln2_b,
    const float* __restrict__ proj_b,
    const short* __restrict__ Wbf, const short* __restrict__ Pbf,
    float* __restrict__ out, float* __restrict__ part)
{
  __shared__ __align__(16) char smem_raw[150784];
  float* MB = (float*)(smem_raw + 0);        // [160]: mask at index j+16, zero outside [0,90)
  float* XB = (float*)(smem_raw + 640);      // [96]
  float* SM = (float*)(smem_raw + 1024);     // [96]
  float* SR = (float*)(smem_raw + 1408);     // [96]
  float* H  = (float*)(smem_raw + 1792);     // [192][92] fp32, PRE-MASKED
  short* YC = (short*)(smem_raw + 72448);    // [192][104] bf16
  short* YT = (short*)(smem_raw + 112384);   // [96][200] bf16
  float* PS = (float*)(smem_raw + 112384);   // alias on YT: [2][16][96] partial sums
  float* HP = (float*)(smem_raw + 72448);    // alias on YC: [64][33] proj output

  const int tid = threadIdx.x;
  const int b = blockIdx.y, tile = blockIdx.x;
  const int t0 = tile*TILE_ - HALO_;

  // ---- setup mask + x0 window
  for (int idx = tid; idx < 160; idx += NT_){
    int j = idx - 16; int t = t0 + j;
    float m = 0.f;
    if (j >= 0 && j < TW_ && t >= 0 && t < TT_) m = xmask[b*TT_ + t];
    MB[idx] = m;
  }
  for (int idx = tid; idx < 96; idx += NT_){
    int t = t0 + idx; float v = 0.f;
    if (idx < TW_ && t >= 0 && t < TT_) v = x[(b*2)*TT_ + t];
    XB[idx] = v;
  }
  __syncthreads();
  // ---- h0 = (pre_w * x0 + pre_b) * mask   (pre-masked H)
  for (int g = tid; g < CC_*23; g += NT_){
    int c = g / 23, jq = g - c*23;
    float w = pre_w[c], bb = pre_b[c];
    f32x4 xv = *(f32x4*)&XB[jq*4];
    f32x4 mv = *(f32x4*)&MB[16 + jq*4];
    f32x4 hv;
    #pragma unroll
    for (int e=0;e<4;e++) hv[e] = (w*xv[e] + bb)*mv[e];
    *(f32x4*)&H[c*HS_ + jq*4] = hv;
  }
  __syncthreads();

  // ---- 3 WN layers
  #pragma unroll 1
  for (int li = 0; li < 3; ++li){
    const int jlo = (li==0) ? 1 : ((li==1) ? 4 : 13);
    const int jhi = (li==0) ? 89 : ((li==1) ? 86 : 77);
    const float* sw = sep_w + li*CC_*3;
    const float* sb = sep_b + li*CC_;

    if (li == 0)      dw_pass<1>(H, YC, sw, sb, tid);
    else if (li == 1) dw_pass<3>(H, YC, sw, sb, tid);
    else              dw_pass<9>(H, YC, sw, sb, tid);
    __syncthreads();

    ln_stats(YC, PS, tid);  __syncthreads();
    ln_combine(PS, SM, SR, tid); __syncthreads();

    // ---- transpose + LN1 + gelu -> y_t[j][c] bf16 (zero outside valid rows)
    {
      const float* g1 = ln1_g + li*CC_;
      const float* b1 = ln1_b + li*CC_;
      for (int g = tid; g < 48*24; g += NT_){
        int c4 = g % 48, t4 = g / 48;
        int c0 = c4*4, tt2 = t4*4;
        f32x4 g1v = *(const f32x4*)&g1[c0];
        f32x4 b1v = *(const f32x4*)&b1[c0];
        f32x4 mv = *(f32x4*)&SM[tt2], rv = *(f32x4*)&SR[tt2];
        float vals[4][4];
        #pragma unroll
        for (int rr=0; rr<4; rr++){
          s16x4 yv = *(s16x4*)&YC[(c0+rr)*YCS_ + tt2];
          #pragma unroll
          for (int e=0;e<4;e++)
            vals[rr][e] = (bf2f(yv[e]) - mv[e]) * rv[e] * g1v[rr] + b1v[rr];
        }
        #pragma unroll
        for (int e=0;e<4;e++){
          int t = tt2 + e;
          bool ok = (t >= jlo) && (t < jhi);
          s16x4 o;
          #pragma unroll
          for (int rr=0; rr<4; rr++)
            o[rr] = f2bf(ok ? gelu_f(vals[rr][e]) : 0.f);
          *(s16x4*)&YT[t*YTS_ + c0] = o;
        }
      }
    }
    __syncthreads();

    // ---- pointwise 192x192 GEMM via MFMA: 12 waves, 1 M-tile x 6 N-tiles each
    {
      int w = tid >> 6, lane = tid & 63, l16 = lane & 15, q = lane >> 4;
      if (w < 12){
        f32x4 acc[6];
        #pragma unroll
        for (int s=0;s<6;s++){ f32x4 z = {0.f,0.f,0.f,0.f}; acc[s] = z; }
        const short* Wl = Wbf + li*CC_*CC_;
        #pragma unroll
        for (int kk=0; kk<6; ++kk){
          s16x8 a = *(const s16x8*)&Wl[(w*16 + l16)*CC_ + kk*32 + q*8];
          #pragma unroll
          for (int s=0;s<6;s++){
            s16x8 bv = *(const s16x8*)&YT[(s*16 + l16)*YTS_ + kk*32 + q*8];
            acc[s] = __builtin_amdgcn_mfma_f32_16x16x32_bf16(a, bv, acc[s], 0, 0, 0);
          }
        }
        #pragma unroll
        for (int e=0;e<4;e++){
          int m = w*16 + q*4 + e;
          float bias = pw_b[li*CC_ + m];
          #pragma unroll
          for (int s=0;s<6;s++){
            int j = s*16 + l16;
            YC[m*YCS_ + j] = f2bf(acc[s][e] + bias);
          }
        }
      }
    }
    __syncthreads();

    ln_stats(YC, PS, tid);  __syncthreads();
    ln_combine(PS, SM, SR, tid); __syncthreads();

    // ---- LN2 + gelu + residual, re-mask -> H stays pre-masked
    {
      const float* g2 = ln2_g + li*CC_;
      const float* b2 = ln2_b + li*CC_;
      for (int g = tid; g < CC_*23; g += NT_){
        int c = g / 23, jq = g - c*23;
        int j0 = jq*4;
        float gc = g2[c], bc = b2[c];
        s16x4 yv = *(s16x4*)&YC[c*YCS_ + j0];
        f32x4 mv = *(f32x4*)&SM[j0], rv = *(f32x4*)&SR[j0];
        f32x4 hv = *(f32x4*)&H[c*HS_ + j0];
        f32x4 mk = *(f32x4*)&MB[16 + j0];
        #pragma unroll
        for (int e=0;e<4;e++){
          float v = (bf2f(yv[e]) - mv[e]) * rv[e] * gc + bc;
          hv[e] = (hv[e] + gelu_f(v)) * mk[e];
        }
        *(f32x4*)&H[c*HS_ + j0] = hv;
      }
    }
    __syncthreads();
  }

  // ---- proj input transpose: y_t[n][c] = bf16(h[c][13+n])  (H pre-masked)
  for (int g = tid; g < 64*CC_; g += NT_){
    int n = g & 63, c = g >> 6;
    YT[n*YTS_ + c] = f2bf(H[c*HS_ + HALO_ + n]);
  }
  __syncthreads();
  // ---- proj GEMM (32x192 @ 192x64) via MFMA -> HP[n][m], bias + mask applied
  {
    int w = tid >> 6;
    if (w < 4){
      int lane = tid & 63, l16 = lane & 15, q = lane >> 4;
      int mt = w >> 1, ntp = w & 1;
      f32x4 pacc[2];
      { f32x4 z = {0.f,0.f,0.f,0.f}; pacc[0] = z; pacc[1] = z; }
      #pragma unroll
      for (int kk=0; kk<6; ++kk){
        s16x8 a = *(const s16x8*)&Pbf[(mt*16 + l16)*CC_ + kk*32 + q*8];
        #pragma unroll
        for (int s=0;s<2;s++){
          s16x8 bv = *(const s16x8*)&YT[((ntp*2+s)*16 + l16)*YTS_ + kk*32 + q*8];
          pacc[s] = __builtin_amdgcn_mfma_f32_16x16x32_bf16(a, bv, pacc[s], 0, 0, 0);
        }
      }
      #pragma unroll
      for (int s=0;s<2;s++)
        #pragma unroll
        for (int e=0;e<4;e++){
          int m = mt*16 + q*4 + e;
          if (m < 29){
            int n = (ntp*2+s)*16 + l16;
            HP[n*33 + m] = (pacc[s][e] + proj_b[m]) * MB[16 + HALO_ + n];
          }
        }
    }
  }
  __syncthreads();

  // ---- rational-quadratic spline, one thread per t
  if (tid < 64){
    const int n = tid;
    const int tg = tile*TILE_ + n;
    const float msk = MB[16 + HALO_ + n];
    const float* hp = &HP[n*33];
    const float inv_s = 0.07216878364870323f;  // 1/sqrt(192)
    float uw[10], uh[10], ud9[9];
    #pragma unroll
    for (int k=0;k<10;k++){ uw[k] = hp[k]*inv_s; uh[k] = hp[10+k]*inv_s; }
    #pragma unroll
    for (int k=0;k<9;k++) ud9[k] = hp[20+k];

    float cumw[11], cumh[11];
    {
      float mx = uw[0];
      #pragma unroll
      for (int k=1;k<10;k++) mx = fmaxf(mx, uw[k]);
      float ex[10]; float ss = 0.f;
      #pragma unroll
      for (int k=0;k<10;k++){ ex[k] = __expf(uw[k]-mx); ss += ex[k]; }
      float inv = 1.0f/ss;
      cumw[0] = -5.f; float cw = 0.f;
      #pragma unroll
      for (int k=0;k<10;k++){ float wk = 0.001f + 0.99f*(ex[k]*inv); cw += wk; cumw[k+1] = 10.f*cw - 5.f; }
      cumw[10] = 5.f;
    }
    {
      float mx = uh[0];
      #pragma unroll
      for (int k=1;k<10;k++) mx = fmaxf(mx, uh[k]);
      float ex[10]; float ss = 0.f;
      #pragma unroll
      for (int k=0;k<10;k++){ ex[k] = __expf(uh[k]-mx); ss += ex[k]; }
      float inv = 1.0f/ss;
      cumh[0] = -5.f; float ch = 0.f;
      #pragma unroll
      for (int k=0;k<10;k++){ float hk = 0.001f + 0.99f*(ex[k]*inv); ch += hk; cumh[k+1] = 10.f*ch - 5.f; }
      cumh[10] = 5.f;
    }
    float dv[11];
    dv[0] = 1.0f; dv[10] = 1.0f;
    #pragma unroll
    for (int k=0;k<9;k++){
      float u = ud9[k];
      float sp = (u > 15.f) ? u : log1pf(__expf(u));
      dv[k+1] = 0.001f + sp;
    }

    const float x1 = x[(b*2+1)*TT_ + tg];
    const float xin = fminf(fmaxf(x1, -5.f), 5.f);
    int cnt = 0;
    #pragma unroll
    for (int k=0;k<11;k++){
      float lk = cumw[k] + ((k==10) ? 1e-6f : 0.f);
      cnt += (xin >= lk) ? 1 : 0;
    }
    int bin = cnt - 1;
    bin = (bin < 0) ? 0 : ((bin > 9) ? 9 : bin);

    float icw=0.f, iw=1.f, ich=0.f, ih=1.f, dl=1.f, dr=1.f;
    #pragma unroll
    for (int k=0;k<10;k++){
      if (bin == k){
        icw = cumw[k]; iw = cumw[k+1]-cumw[k];
        ich = cumh[k]; ih = cumh[k+1]-cumh[k];
        dl = dv[k]; dr = dv[k+1];
      }
    }
    float delta = ih/iw;
    float th = (xin - icw)/iw;
    float t1m = th*(1.f-th);
    float num = ih*(delta*th*th + dl*t1m);
    float den = delta + (dl + dr - 2.f*delta)*t1m;
    float yv = ich + num/den;
    float omt = 1.f - th;
    float dnum = delta*delta*(dr*th*th + 2.f*delta*t1m + dl*omt*omt);
    float lad = logf(dnum) - 2.f*logf(den);
    bool inside = (x1 >= -5.f) && (x1 <= 5.f);
    float outv = inside ? yv : x1;
    float ladv = inside ? lad : 0.f;

    out[(b*2)*TT_ + tg]   = x[(b*2)*TT_ + tg] * msk;
    out[(b*2+1)*TT_ + tg] = outv * msk;

    float lsum = ladv * msk;
    #pragma unroll
    for (int off = 32; off > 0; off >>= 1) lsum += __shfl_xor(lsum, off);
    if (tid == 0) part[b*64 + tile] = lsum;
  }
}

// ---- pre-pass: convert pw_w / proj_w to bf16 in workspace
__global__ void convflow_pre(const float* __restrict__ pw_w, const float* __restrict__ proj_w,
                             short* __restrict__ Wbf, short* __restrict__ Pbf){
  int idx = blockIdx.x*256 + threadIdx.x;
  if (idx < 110592) Wbf[idx] = f2bf(pw_w[idx]);
  if (idx < 32*192){
    int m = idx / 192, k = idx - m*192;
    Pbf[idx] = (m < 29) ? f2bf(proj_w[m*192 + k]) : (short)0;
  }
}

// ---- logdet reduction: 64 tiles per batch
__global__ void convflow_logdet(const float* __restrict__ part, float* __restrict__ out){
  int bb = threadIdx.x;
  if (bb < 64){
    float s = 0.f;
    for (int k=0;k<64;k++) s += part[bb*64 + k];
    out[524288 + bb] = s;
  }
}

extern "C" void kernel_launch(void* const* d_in, const int* in_sizes, int n_in,
                              void* d_out, int out_size, void* d_ws, size_t ws_size,
                              hipStream_t stream) {
  const float* x      = (const float*)d_in[0];
  const float* xmask  = (const float*)d_in[1];
  const float* pre_w  = (const float*)d_in[2];
  const float* pre_b  = (const float*)d_in[3];
  const float* sep_w  = (const float*)d_in[4];
  const float* sep_b  = (const float*)d_in[5];
  const float* pw_w   = (const float*)d_in[6];
  const float* pw_b   = (const float*)d_in[7];
  const float* ln1_g  = (const float*)d_in[8];
  const float* ln1_b  = (const float*)d_in[9];
  const float* ln2_g  = (const float*)d_in[10];
  const float* ln2_b  = (const float*)d_in[11];
  const float* proj_w = (const float*)d_in[12];
  const float* proj_b = (const float*)d_in[13];

  short* Wbf = (short*)d_ws;                              // 3*192*192 bf16
  short* Pbf = (short*)((char*)d_ws + 221184);            // 32*192 bf16
  float* part = (float*)((char*)d_ws + 233472);           // 4096 floats
  float* out = (float*)d_out;

  convflow_pre<<<432, 256, 0, stream>>>(pw_w, proj_w, Wbf, Pbf);
  dim3 grid(64, 64);  // (tile, batch)
  convflow_main<<<grid, NT_, 0, stream>>>(x, xmask, pre_w, pre_b, sep_w, sep_b, pw_b,
                                          ln1_g, ln1_b, ln2_g, ln2_b, proj_b,
                                          Wbf, Pbf, out, part);
  convflow_logdet<<<1, 64, 0, stream>>>(part, out);
}